// Round 1
// baseline (2200.378 us; speedup 1.0000x reference)
//
#include <hip/hip_runtime.h>
#include <hip/hip_bf16.h>

#define E_EDGES 131072
#define NNODES  8192
#define NB      16384   // N_NODES * BATCH rows
#define HID     256
#define EDIM    64
#define MLPH    512
#define OUTD    128
#define NIT     3

typedef short s16x4 __attribute__((ext_vector_type(4)));
typedef short s16x8 __attribute__((ext_vector_type(8)));
typedef float f32x4 __attribute__((ext_vector_type(4)));

__device__ __forceinline__ short f2bf(float f){
  unsigned int x = __builtin_bit_cast(unsigned int, f);
  x += 0x7fffu + ((x >> 16) & 1u);          // RNE
  return (short)(x >> 16);
}
__device__ __forceinline__ float bf2f(short s){
  unsigned int x = ((unsigned int)(unsigned short)s) << 16;
  return __builtin_bit_cast(float, x);
}

// ---------------------------------------------------------------------------
// Generic 64x64-tile MFMA GEMM: C[M,N] = A[M,K] * Bt[N,K]^T (+ epilogues)
// MODE 0: Cbf = bf16(acc + bias[col])           (proj P, E1)
// MODE 1: m-update: v = acc + m_old + deg*b2 -> Cf (m) and Cbf (mh m-part)
// MODE 2: Cf = acc (fp32)                       (G1, G2)
// GATHER: A is fp32 edge_feat gathered through CSR eid (for E1)
// ---------------------------------------------------------------------------
template<int MODE, bool GATHER>
__global__ __launch_bounds__(256)
void gemm64(const void* __restrict__ Ap, int lda, const short* __restrict__ Bt, int K,
            float* __restrict__ Cf, short* __restrict__ Cbf, int ldcf, int ldcbf,
            const float* __restrict__ bias, const int* __restrict__ deg,
            const float* __restrict__ b2,
            const int* __restrict__ gat, const int* __restrict__ row_start,
            int node0, int node1)
{
  int p0 = 0;
  int mrows = gridDim.x * 64;
  if (GATHER){
    p0 = row_start[node0];
    mrows = 2 * (row_start[node1] - p0);
    if ((int)blockIdx.x * 64 >= mrows) return;
  }
  const int w  = threadIdx.x >> 6;
  const int l  = threadIdx.x & 63;
  const int lr = l & 15;          // A row / B col within 16-tile
  const int lg = l >> 4;          // k-group (8 contiguous k each)
  const int arow    = blockIdx.x * 64 + w * 16 + lr;
  const int colbase = blockIdx.y * 64;

  f32x4 acc[4];
#pragma unroll
  for (int i = 0; i < 4; ++i) acc[i] = (f32x4){0.f, 0.f, 0.f, 0.f};

  for (int k0 = 0; k0 < K; k0 += 32){
    s16x8 af;
    if (GATHER){
      int r = arow < mrows ? arow : 0;
      int e = gat[p0 + (r >> 1)];
      const float* ap = (const float*)Ap + (size_t)(e * 2 + (r & 1)) * lda + k0 + lg * 8;
      f32x4 f0 = *(const f32x4*)ap;
      f32x4 f1 = *(const f32x4*)(ap + 4);
      af[0]=f2bf(f0[0]); af[1]=f2bf(f0[1]); af[2]=f2bf(f0[2]); af[3]=f2bf(f0[3]);
      af[4]=f2bf(f1[0]); af[5]=f2bf(f1[1]); af[6]=f2bf(f1[2]); af[7]=f2bf(f1[3]);
    } else {
      af = *(const s16x8*)((const short*)Ap + (size_t)arow * lda + k0 + lg * 8);
    }
#pragma unroll
    for (int nf = 0; nf < 4; ++nf){
      s16x8 bfv = *(const s16x8*)(Bt + (size_t)(colbase + nf * 16 + lr) * K + k0 + lg * 8);
      acc[nf] = __builtin_amdgcn_mfma_f32_16x16x32_bf16(af, bfv, acc[nf], 0, 0, 0);
    }
  }

  const int orow0 = blockIdx.x * 64 + w * 16 + lg * 4;  // C/D: row=(l>>4)*4+reg
#pragma unroll
  for (int nf = 0; nf < 4; ++nf){
    int ocol = colbase + nf * 16 + lr;                  // C/D: col=l&15
#pragma unroll
    for (int r = 0; r < 4; ++r){
      int orow = orow0 + r;
      float v = acc[nf][r];
      if (MODE == 0){
        if (!GATHER || orow < mrows){
          if (bias) v += bias[ocol];
          Cbf[(size_t)orow * ldcbf + ocol] = f2bf(v);
        }
      } else if (MODE == 1){
        float mo = Cf[(size_t)orow * ldcf + ocol];
        v += mo + (float)deg[orow >> 1] * b2[ocol];
        Cf[(size_t)orow * ldcf + ocol] = v;
        Cbf[(size_t)orow * ldcbf + ocol] = f2bf(v);
      } else {
        Cf[(size_t)orow * ldcf + ocol] = v;
      }
    }
  }
}

// ---------------------------------------------------------------------------
// Per-node CSR edge kernel: S[n] = sum_{e: dst=n} relu(P1[n] + P2[src] + E1[e])
// block = one node, 256 threads, each thread owns 4 (b,j) slots of the 2x512.
// ---------------------------------------------------------------------------
__global__ __launch_bounds__(256)
void edge_kernel(const short* __restrict__ P, const short* __restrict__ E1,
                 const int* __restrict__ csr_src, const int* __restrict__ row_start,
                 short* __restrict__ S, int node0)
{
  const int n = node0 + blockIdx.x;
  const int t = threadIdx.x;
  const int b = t >> 7;
  const int j = (t & 127) << 2;
  const int p0 = row_start[node0];
  const int ps = row_start[n], pe = row_start[n + 1];

  s16x4 t1 = *(const s16x4*)(P + (size_t)(n * 2 + b) * 1024 + j);  // P1 = dst-part
  float p10 = bf2f(t1[0]), p11 = bf2f(t1[1]), p12 = bf2f(t1[2]), p13 = bf2f(t1[3]);
  float a0 = 0.f, a1 = 0.f, a2 = 0.f, a3 = 0.f;

  for (int p = ps; p < pe; ++p){
    int src = csr_src[p];  // uniform across block -> scalar load
    s16x4 v2 = *(const s16x4*)(P  + (size_t)(src * 2 + b) * 1024 + 512 + j);
    s16x4 v1 = *(const s16x4*)(E1 + (size_t)((p - p0) * 2 + b) * 512 + j);
    float x0 = p10 + bf2f(v2[0]) + bf2f(v1[0]); a0 += fmaxf(x0, 0.f);
    float x1 = p11 + bf2f(v2[1]) + bf2f(v1[1]); a1 += fmaxf(x1, 0.f);
    float x2 = p12 + bf2f(v2[2]) + bf2f(v1[2]); a2 += fmaxf(x2, 0.f);
    float x3 = p13 + bf2f(v2[3]) + bf2f(v1[3]); a3 += fmaxf(x3, 0.f);
  }
  s16x4 o; o[0] = f2bf(a0); o[1] = f2bf(a1); o[2] = f2bf(a2); o[3] = f2bf(a3);
  *(s16x4*)(S + (size_t)(n * 2 + b) * 512 + j) = o;
}

// ------------------------------- CSR build ---------------------------------
__global__ void count_kernel(const int* __restrict__ edst, int* __restrict__ counts){
  int e = blockIdx.x * 256 + threadIdx.x;
  if (e < E_EDGES) atomicAdd(&counts[edst[e]], 1);
}
__global__ void scan_kernel(const int* __restrict__ counts, int* __restrict__ row_start,
                            int* __restrict__ cursor){
  __shared__ int sums[1024];
  int t = threadIdx.x;
  int base = t * 8;
  int loc[8]; int s = 0;
#pragma unroll
  for (int i = 0; i < 8; ++i){ loc[i] = s; s += counts[base + i]; }
  sums[t] = s;
  __syncthreads();
  for (int o = 1; o < 1024; o <<= 1){
    int v = sums[t];
    int u = (t >= o) ? sums[t - o] : 0;
    __syncthreads();
    sums[t] = v + u;
    __syncthreads();
  }
  int excl = (t == 0) ? 0 : sums[t - 1];
#pragma unroll
  for (int i = 0; i < 8; ++i){ int v = excl + loc[i]; row_start[base + i] = v; cursor[base + i] = v; }
  if (t == 1023) row_start[NNODES] = sums[1023];
}
__global__ void fill_kernel(const int* __restrict__ edst, const int* __restrict__ esrc,
                            int* __restrict__ cursor, int* __restrict__ csr_eid,
                            int* __restrict__ csr_src){
  int e = blockIdx.x * 256 + threadIdx.x;
  if (e < E_EDGES){
    int pos = atomicAdd(&cursor[edst[e]], 1);
    csr_eid[pos] = e;
    csr_src[pos] = esrc[e];
  }
}

// --------------------------- weight repacking ------------------------------
__global__ void prep_weights(const float* __restrict__ W1, const float* __restrict__ W2,
                             const float* __restrict__ Wr, const float* __restrict__ Ur,
                             const float* __restrict__ Wz, const float* __restrict__ Uz,
                             const float* __restrict__ Wh, const float* __restrict__ Uh,
                             short* __restrict__ BtP, short* __restrict__ BtE,
                             short* __restrict__ BtW2, short* __restrict__ BtG1,
                             short* __restrict__ BtUh)
{
  int id = blockIdx.x * 256 + threadIdx.x;
  if (id < 262144){                       // BtP [1024][256]: [A1|A2]^T
    int j = id >> 8, k = id & 255;
    float v = (j < 512) ? W1[(size_t)k * 512 + j] : W1[(size_t)(256 + k) * 512 + (j - 512)];
    BtP[id] = f2bf(v);
  } else if (id < 294912){                // BtE [512][64]: A3^T
    int i2 = id - 262144; int j = i2 >> 6, c = i2 & 63;
    BtE[i2] = f2bf(W1[(size_t)(512 + c) * 512 + j]);
  } else if (id < 425984){                // BtW2 [256][512]
    int i2 = id - 294912; int n = i2 >> 9, k = i2 & 511;
    BtW2[i2] = f2bf(W2[(size_t)k * 256 + n]);
  } else if (id < 819200){                // BtG1 [768][512]
    int i2 = id - 425984; int j = i2 >> 9, k = i2 & 511;
    float v;
    if (k < 256){
      v = (j < 256) ? Wr[k * 256 + j] : (j < 512) ? Wz[k * 256 + (j - 256)] : Wh[k * 256 + (j - 512)];
    } else {
      int kk = k - 256;
      v = (j < 256) ? Ur[kk * 256 + j] : (j < 512) ? Uz[kk * 256 + (j - 256)] : 0.f;
    }
    BtG1[i2] = f2bf(v);
  } else if (id < 884736){                // BtUh [256][256]
    int i2 = id - 819200; int n = i2 >> 8, k = i2 & 255;
    BtUh[i2] = f2bf(Uh[(size_t)k * 256 + n]);
  }
}

// ------------------------------ GRU elementwise ----------------------------
__global__ __launch_bounds__(256)
void gru_elem1(const float* __restrict__ G1, const float* __restrict__ h,
               const float* __restrict__ br, const float* __restrict__ bz,
               short* __restrict__ rh, float* __restrict__ zbuf)
{
  int gi = blockIdx.x * 256 + threadIdx.x;
  int row = gi >> 6, c = (gi & 63) << 2;
  f32x4 gr  = *(const f32x4*)(G1 + (size_t)row * 768 + c);
  f32x4 gz  = *(const f32x4*)(G1 + (size_t)row * 768 + 256 + c);
  f32x4 hv  = *(const f32x4*)(h  + (size_t)row * 256 + c);
  f32x4 brv = *(const f32x4*)(br + c);
  f32x4 bzv = *(const f32x4*)(bz + c);
  s16x4 rhv; f32x4 zv;
#pragma unroll
  for (int jj = 0; jj < 4; ++jj){
    float r = 1.f / (1.f + __expf(-(gr[jj] + brv[jj])));
    float z = 1.f / (1.f + __expf(-(gz[jj] + bzv[jj])));
    rhv[jj] = f2bf(r * hv[jj]);
    zv[jj]  = z;
  }
  *(s16x4*)(rh  + (size_t)row * 256 + c) = rhv;
  *(f32x4*)(zbuf + (size_t)row * 256 + c) = zv;
}
__global__ __launch_bounds__(256)
void gru_elem2(const float* __restrict__ G1, const float* __restrict__ G2,
               const float* __restrict__ zbuf, const float* __restrict__ bh,
               float* __restrict__ h, short* __restrict__ mh)
{
  int gi = blockIdx.x * 256 + threadIdx.x;
  int row = gi >> 6, c = (gi & 63) << 2;
  f32x4 pw  = *(const f32x4*)(G1 + (size_t)row * 768 + 512 + c);
  f32x4 g2  = *(const f32x4*)(G2 + (size_t)row * 256 + c);
  f32x4 bhv = *(const f32x4*)(bh + c);
  f32x4 zv  = *(const f32x4*)(zbuf + (size_t)row * 256 + c);
  f32x4 hv  = *(const f32x4*)(h + (size_t)row * 256 + c);
  f32x4 hn; s16x4 hb;
#pragma unroll
  for (int jj = 0; jj < 4; ++jj){
    float ht = tanhf(pw[jj] + g2[jj] + bhv[jj]);
    float x  = (1.f - zv[jj]) * hv[jj] + zv[jj] * ht;
    hn[jj] = x; hb[jj] = f2bf(x);
  }
  *(f32x4*)(h + (size_t)row * 256 + c) = hn;
  *(s16x4*)(mh + (size_t)row * 512 + 256 + c) = hb;
}

// -------------------------------- readout ----------------------------------
__global__ __launch_bounds__(256)
void readout1(const float* __restrict__ h, float* __restrict__ g){
  int t = threadIdx.x;
  float a0 = 0.f, a1 = 0.f;
  int n0 = blockIdx.x * 32;
  for (int n = n0; n < n0 + 32; ++n){
    const float* hp = h + (size_t)n * 512;
    a0 += hp[t];
    a1 += hp[t + 256];
  }
  atomicAdd(&g[t], a0);
  atomicAdd(&g[t + 256], a1);
}
__global__ __launch_bounds__(256)
void readout2(const float* __restrict__ g, const float* __restrict__ Wo,
              const float* __restrict__ bo, float* __restrict__ out){
  int t = threadIdx.x;
  int b = t >> 7, o = t & 127;
  float s = bo[o];
  for (int c = 0; c < 256; ++c) s += g[b * 256 + c] * Wo[c * 128 + o];
  out[b * 128 + o] = s;
}

// ===========================================================================
extern "C" void kernel_launch(void* const* d_in, const int* in_sizes, int n_in,
                              void* d_out, int out_size, void* d_ws, size_t ws_size,
                              hipStream_t stream)
{
  const float* ef  = (const float*)d_in[0];
  const float* W1  = (const float*)d_in[1];
  const float* b1  = (const float*)d_in[2];
  const float* W2  = (const float*)d_in[3];
  const float* b2  = (const float*)d_in[4];
  const float* Wr  = (const float*)d_in[5];
  const float* Ur  = (const float*)d_in[6];
  const float* br  = (const float*)d_in[7];
  const float* Wz  = (const float*)d_in[8];
  const float* Uz  = (const float*)d_in[9];
  const float* bz  = (const float*)d_in[10];
  const float* Wh  = (const float*)d_in[11];
  const float* Uh  = (const float*)d_in[12];
  const float* bh  = (const float*)d_in[13];
  const float* Wo  = (const float*)d_in[14];
  const float* bo  = (const float*)d_in[15];
  const int* esrc  = (const int*)d_in[16];
  const int* edst  = (const int*)d_in[17];

  char* base = (char*)d_ws;
  size_t off = 0;
  auto alloc = [&](size_t bytes) -> char* {
    off = (off + 255) & ~(size_t)255;
    char* p = base + off;
    off += bytes;
    return p;
  };
  float* h    = (float*)alloc((size_t)NB * 256 * 4);
  float* m    = (float*)alloc((size_t)NB * 256 * 4);
  short* mh   = (short*)alloc((size_t)NB * 512 * 2);   // [m_bf | h_bf]
  short* P    = (short*)alloc((size_t)NB * 1024 * 2);  // [P1 | P2]
  short* S    = (short*)alloc((size_t)NB * 512 * 2);
  float* G1   = (float*)alloc((size_t)NB * 768 * 4);
  float* G2   = (float*)alloc((size_t)NB * 256 * 4);
  short* rh   = (short*)alloc((size_t)NB * 256 * 2);
  float* zb   = (float*)alloc((size_t)NB * 256 * 4);
  short* BtP  = (short*)alloc(262144 * 2);
  short* BtE  = (short*)alloc(32768 * 2);
  short* BtW2 = (short*)alloc(131072 * 2);
  short* BtG1 = (short*)alloc(393216 * 2);
  short* BtUh = (short*)alloc(65536 * 2);
  int* counts = (int*)alloc(NNODES * 4);
  int* rs     = (int*)alloc((NNODES + 1) * 4);
  int* cursor = (int*)alloc(NNODES * 4);
  int* ceid   = (int*)alloc(E_EDGES * 4);
  int* csrc   = (int*)alloc(E_EDGES * 4);
  float* g    = (float*)alloc(512 * 4);
  off = (off + 255) & ~(size_t)255;
  size_t avail = ws_size > off ? ws_size - off : 0;
  short* E1 = (short*)(base + off);

  // E1 chunking: full is 268 MB; fall back to per-iter chunked recompute.
  size_t e1_full = (size_t)E_EDGES * 2 * MLPH * 2;
  int nchunks = 1;
  size_t cap_edges = E_EDGES;
  if (avail < e1_full){
    nchunks = 0;
    for (int nc = 2; nc <= 64; nc <<= 1){
      size_t cap = (size_t)((double)E_EDGES / nc * 1.25) + 256;
      if (cap * 2 * MLPH * 2 <= avail){ nchunks = nc; cap_edges = cap; break; }
    }
    if (!nchunks){ nchunks = 64; cap_edges = avail / (2 * MLPH * 2); }
  }

  dim3 blk(256);

  // ------------------------------- prep ----------------------------------
  hipMemsetAsync(h,  0, (size_t)NB * 256 * 4, stream);
  hipMemsetAsync(m,  0, (size_t)NB * 256 * 4, stream);
  hipMemsetAsync(mh, 0, (size_t)NB * 512 * 2, stream);
  hipMemsetAsync(g,  0, 512 * 4, stream);
  hipMemsetAsync(counts, 0, NNODES * 4, stream);
  prep_weights<<<3456, blk, 0, stream>>>(W1, W2, Wr, Ur, Wz, Uz, Wh, Uh,
                                         BtP, BtE, BtW2, BtG1, BtUh);
  count_kernel<<<512, blk, 0, stream>>>(edst, counts);
  scan_kernel<<<1, 1024, 0, stream>>>(counts, rs, cursor);
  fill_kernel<<<512, blk, 0, stream>>>(edst, esrc, cursor, ceid, csrc);

  auto launch_e1 = [&](int n0, int n1, size_t capE){
    int gx = (int)((2 * capE + 63) / 64);
    gemm64<0, true><<<dim3(gx, MLPH / 64), blk, 0, stream>>>(
        (const void*)ef, EDIM, BtE, EDIM, nullptr, E1, 0, MLPH, b1,
        nullptr, nullptr, ceid, rs, n0, n1);
  };
  if (nchunks == 1) launch_e1(0, NNODES, E_EDGES);   // iteration-invariant

  // ----------------------------- iterations ------------------------------
  for (int it = 0; it < NIT; ++it){
    // P = h @ [A1 | A2]   (A = h_bf = mh cols 256..511)
    gemm64<0, false><<<dim3(256, 16), blk, 0, stream>>>(
        (const void*)(mh + 256), 512, BtP, 256, nullptr, P, 0, 1024, nullptr,
        nullptr, nullptr, nullptr, nullptr, 0, 0);

    if (nchunks == 1){
      edge_kernel<<<NNODES, blk, 0, stream>>>(P, E1, csrc, rs, S, 0);
    } else {
      int npc = NNODES / nchunks;
      for (int c = 0; c < nchunks; ++c){
        launch_e1(c * npc, (c + 1) * npc, cap_edges);
        edge_kernel<<<npc, blk, 0, stream>>>(P, E1, csrc, rs, S, c * npc);
      }
    }

    // m += S @ W2 + deg*b2 ; write fp32 m and bf16 into mh[:,0:256]
    gemm64<1, false><<<dim3(256, 4), blk, 0, stream>>>(
        (const void*)S, 512, BtW2, 512, m, mh, 256, 512, nullptr,
        counts, b2, nullptr, nullptr, 0, 0);

    // G1 = [m|h] @ [[Wr|Wz|Wh],[Ur|Uz|0]]
    gemm64<2, false><<<dim3(256, 12), blk, 0, stream>>>(
        (const void*)mh, 512, BtG1, 512, G1, nullptr, 768, 0, nullptr,
        nullptr, nullptr, nullptr, nullptr, 0, 0);

    gru_elem1<<<4096, blk, 0, stream>>>(G1, h, br, bz, rh, zb);

    // G2 = (r*h) @ Uh
    gemm64<2, false><<<dim3(256, 4), blk, 0, stream>>>(
        (const void*)rh, 256, BtUh, 256, G2, nullptr, 256, 0, nullptr,
        nullptr, nullptr, nullptr, nullptr, 0, 0);

    gru_elem2<<<4096, blk, 0, stream>>>(G1, G2, zb, bh, h, mh);
  }

  // ------------------------------ readout --------------------------------
  readout1<<<256, blk, 0, stream>>>(h, g);
  readout2<<<1, blk, 0, stream>>>(g, Wo, bo, (float*)d_out);
}

// Round 2
// 1919.718 us; speedup vs baseline: 1.1462x; 1.1462x over previous
//
#include <hip/hip_runtime.h>
#include <hip/hip_bf16.h>

#define E_EDGES 131072
#define NNODES  8192
#define NB      16384   // N_NODES * BATCH rows
#define HID     256
#define EDIM    64
#define MLPH    512
#define OUTD    128
#define NIT     3

typedef short s16x4 __attribute__((ext_vector_type(4)));
typedef short s16x8 __attribute__((ext_vector_type(8)));
typedef float f32x4 __attribute__((ext_vector_type(4)));

__device__ __forceinline__ short f2bf(float f){
  unsigned int x = __builtin_bit_cast(unsigned int, f);
  x += 0x7fffu + ((x >> 16) & 1u);          // RNE
  return (short)(x >> 16);
}
__device__ __forceinline__ float bf2f(short s){
  unsigned int x = ((unsigned int)(unsigned short)s) << 16;
  return __builtin_bit_cast(float, x);
}

__device__ __forceinline__ void gload_lds16(const void* g, void* l){
  __builtin_amdgcn_global_load_lds(
      (const __attribute__((address_space(1))) void*)g,
      (__attribute__((address_space(3))) void*)l, 16, 0, 0);
}

// ---------------------------------------------------------------------------
// m97-structure GEMM: C[M,N] = A[M,K] * Bt[N,K]^T, 128x128 tile, BK=64,
// 256 threads = 2x2 waves, each wave 64x64 out (4x4 frags of 16x16x32 bf16).
// LDS staged with global_load_lds width=16 (linear LDS; per-lane global src).
// MODE 0: Cbf = bf16(acc + bias[col])           (P proj, E1)
// MODE 1: v = acc + m_old + deg*b2 -> Cf(m), Cbf(mh m-part)
// MODE 2: Cf = acc (fp32)                       (G1, G2)
// GATHER: A rows gathered through CSR eid (E1); row R -> edge gat[p0+(R>>1)],
//         batch R&1. Out rows relative to chunk base.
// ---------------------------------------------------------------------------
template<int MODE, bool GATHER>
__global__ __launch_bounds__(256, 3)
void gemm128(const short* __restrict__ A, int lda, const short* __restrict__ Bt,
             int K, float* __restrict__ Cf, short* __restrict__ Cbf,
             int ldcf, int ldcbf,
             const float* __restrict__ bias, const int* __restrict__ deg,
             const float* __restrict__ b2,
             const int* __restrict__ gat, const int* __restrict__ row_start,
             int node0, int node1)
{
  __shared__ __align__(16) short As[128 * 64];
  __shared__ __align__(16) short Bs[128 * 64];

  int p0 = 0, mrows = 1 << 30;
  if (GATHER){
    p0 = row_start[node0];
    mrows = 2 * (row_start[node1] - p0);
    if ((int)blockIdx.x * 128 >= mrows) return;
  }
  const int t  = threadIdx.x;
  const int w  = t >> 6, l = t & 63;
  const int lr = l & 15, lg = l >> 4;
  const int wr = w >> 1, wc = w & 1;
  const int browbase = blockIdx.x * 128;
  const int bcolbase = blockIdx.y * 128;

  const int srow = t >> 3;          // staging row 0..31 (+32 per issue)
  const int scol = (t & 7) * 8;     // staging k-offset (elements)

  f32x4 acc[4][4];
#pragma unroll
  for (int m = 0; m < 4; ++m)
#pragma unroll
    for (int n = 0; n < 4; ++n) acc[m][n] = (f32x4){0.f, 0.f, 0.f, 0.f};

  for (int k0 = 0; k0 < K; k0 += 64){
    __syncthreads();                 // previous compute done before overwrite
#pragma unroll
    for (int i = 0; i < 4; ++i){
      int row = srow + i * 32;
      const short* gp;
      if (GATHER){
        int R = browbase + row;
        int p = p0 + (R >> 1);
        if (p > E_EDGES - 1) p = E_EDGES - 1;   // clamp (masked at epilogue)
        int e = gat[p];
        gp = A + (size_t)(e * 2 + (R & 1)) * lda + scol;   // K=64, k0==0
      } else {
        gp = A + (size_t)(browbase + row) * lda + k0 + scol;
      }
      gload_lds16(gp, (char*)As + w * 1024 + i * 4096);
    }
#pragma unroll
    for (int i = 0; i < 4; ++i){
      const short* gp = Bt + (size_t)(bcolbase + srow + i * 32) * K + k0 + scol;
      gload_lds16(gp, (char*)Bs + w * 1024 + i * 4096);
    }
    __syncthreads();                 // drains vmcnt before barrier (compiler)

#pragma unroll
    for (int kk = 0; kk < 2; ++kk){
      s16x8 a[4], b[4];
#pragma unroll
      for (int m = 0; m < 4; ++m)
        a[m] = *(const s16x8*)(As + (wr * 64 + m * 16 + lr) * 64 + kk * 32 + lg * 8);
#pragma unroll
      for (int n = 0; n < 4; ++n)
        b[n] = *(const s16x8*)(Bs + (wc * 64 + n * 16 + lr) * 64 + kk * 32 + lg * 8);
#pragma unroll
      for (int m = 0; m < 4; ++m)
#pragma unroll
        for (int n = 0; n < 4; ++n)
          acc[m][n] = __builtin_amdgcn_mfma_f32_16x16x32_bf16(a[m], b[n], acc[m][n], 0, 0, 0);
    }
  }

  // epilogue: C/D frag layout col=l&15, row=(l>>4)*4+r  [m89]
#pragma unroll
  for (int m = 0; m < 4; ++m){
    int orow0 = browbase + wr * 64 + m * 16 + lg * 4;
#pragma unroll
    for (int n = 0; n < 4; ++n){
      int ocol = bcolbase + wc * 64 + n * 16 + lr;
#pragma unroll
      for (int r = 0; r < 4; ++r){
        int orow = orow0 + r;
        float v = acc[m][n][r];
        if (MODE == 0){
          if (!GATHER || orow < mrows){
            if (bias) v += bias[ocol];
            Cbf[(size_t)orow * ldcbf + ocol] = f2bf(v);
          }
        } else if (MODE == 1){
          float mo = Cf[(size_t)orow * ldcf + ocol];
          v += mo + (float)deg[orow >> 1] * b2[ocol];
          Cf[(size_t)orow * ldcf + ocol] = v;
          Cbf[(size_t)orow * ldcbf + ocol] = f2bf(v);
        } else {
          Cf[(size_t)orow * ldcf + ocol] = v;
        }
      }
    }
  }
}

// --------------------------- ef -> bf16 conversion -------------------------
__global__ __launch_bounds__(256)
void cvt_ef(const float* __restrict__ ef, short* __restrict__ ebf){
  size_t i = (size_t)(blockIdx.x * 256 + threadIdx.x) * 8;
  f32x4 f0 = *(const f32x4*)(ef + i);
  f32x4 f1 = *(const f32x4*)(ef + i + 4);
  s16x8 o;
  o[0]=f2bf(f0[0]); o[1]=f2bf(f0[1]); o[2]=f2bf(f0[2]); o[3]=f2bf(f0[3]);
  o[4]=f2bf(f1[0]); o[5]=f2bf(f1[1]); o[6]=f2bf(f1[2]); o[7]=f2bf(f1[3]);
  *(s16x8*)(ebf + i) = o;
}

// ---------------------------------------------------------------------------
// Per-node CSR edge kernel: S[n] = sum_{e: dst=n} relu(P1[n] + P2[src] + E1[e])
// ---------------------------------------------------------------------------
__global__ __launch_bounds__(256)
void edge_kernel(const short* __restrict__ P, const short* __restrict__ E1,
                 const int* __restrict__ csr_src, const int* __restrict__ row_start,
                 short* __restrict__ S, int node0)
{
  const int n = node0 + blockIdx.x;
  const int t = threadIdx.x;
  const int b = t >> 7;
  const int j = (t & 127) << 2;
  const int p0 = row_start[node0];
  const int ps = row_start[n], pe = row_start[n + 1];

  s16x4 t1 = *(const s16x4*)(P + (size_t)(n * 2 + b) * 1024 + j);  // P1 (dst)
  float p10 = bf2f(t1[0]), p11 = bf2f(t1[1]), p12 = bf2f(t1[2]), p13 = bf2f(t1[3]);
  float a0 = 0.f, a1 = 0.f, a2 = 0.f, a3 = 0.f;

  for (int p = ps; p < pe; ++p){
    int src = csr_src[p];  // uniform across block -> scalar load
    s16x4 v2 = *(const s16x4*)(P  + (size_t)(src * 2 + b) * 1024 + 512 + j);
    s16x4 v1 = *(const s16x4*)(E1 + (size_t)((p - p0) * 2 + b) * 512 + j);
    float x0 = p10 + bf2f(v2[0]) + bf2f(v1[0]); a0 += fmaxf(x0, 0.f);
    float x1 = p11 + bf2f(v2[1]) + bf2f(v1[1]); a1 += fmaxf(x1, 0.f);
    float x2 = p12 + bf2f(v2[2]) + bf2f(v1[2]); a2 += fmaxf(x2, 0.f);
    float x3 = p13 + bf2f(v2[3]) + bf2f(v1[3]); a3 += fmaxf(x3, 0.f);
  }
  s16x4 o; o[0] = f2bf(a0); o[1] = f2bf(a1); o[2] = f2bf(a2); o[3] = f2bf(a3);
  *(s16x4*)(S + (size_t)(n * 2 + b) * 512 + j) = o;
}

// ------------------------------- CSR build ---------------------------------
__global__ void count_kernel(const int* __restrict__ edst, int* __restrict__ counts){
  int e = blockIdx.x * 256 + threadIdx.x;
  if (e < E_EDGES) atomicAdd(&counts[edst[e]], 1);
}
__global__ void scan_kernel(const int* __restrict__ counts, int* __restrict__ row_start,
                            int* __restrict__ cursor){
  __shared__ int sums[1024];
  int t = threadIdx.x;
  int base = t * 8;
  int loc[8]; int s = 0;
#pragma unroll
  for (int i = 0; i < 8; ++i){ loc[i] = s; s += counts[base + i]; }
  sums[t] = s;
  __syncthreads();
  for (int o = 1; o < 1024; o <<= 1){
    int v = sums[t];
    int u = (t >= o) ? sums[t - o] : 0;
    __syncthreads();
    sums[t] = v + u;
    __syncthreads();
  }
  int excl = (t == 0) ? 0 : sums[t - 1];
#pragma unroll
  for (int i = 0; i < 8; ++i){ int v = excl + loc[i]; row_start[base + i] = v; cursor[base + i] = v; }
  if (t == 1023) row_start[NNODES] = sums[1023];
}
__global__ void fill_kernel(const int* __restrict__ edst, const int* __restrict__ esrc,
                            int* __restrict__ cursor, int* __restrict__ csr_eid,
                            int* __restrict__ csr_src){
  int e = blockIdx.x * 256 + threadIdx.x;
  if (e < E_EDGES){
    int pos = atomicAdd(&cursor[edst[e]], 1);
    csr_eid[pos] = e;
    csr_src[pos] = esrc[e];
  }
}

// --------------------------- weight repacking ------------------------------
__global__ void prep_weights(const float* __restrict__ W1, const float* __restrict__ W2,
                             const float* __restrict__ Wr, const float* __restrict__ Ur,
                             const float* __restrict__ Wz, const float* __restrict__ Uz,
                             const float* __restrict__ Wh, const float* __restrict__ Uh,
                             short* __restrict__ BtP, short* __restrict__ BtE,
                             short* __restrict__ BtW2, short* __restrict__ BtG1,
                             short* __restrict__ BtUh)
{
  int id = blockIdx.x * 256 + threadIdx.x;
  if (id < 262144){                       // BtP [1024][256]: [A1|A2]^T
    int j = id >> 8, k = id & 255;
    float v = (j < 512) ? W1[(size_t)k * 512 + j] : W1[(size_t)(256 + k) * 512 + (j - 512)];
    BtP[id] = f2bf(v);
  } else if (id < 294912){                // BtE [512][64]: A3^T
    int i2 = id - 262144; int j = i2 >> 6, c = i2 & 63;
    BtE[i2] = f2bf(W1[(size_t)(512 + c) * 512 + j]);
  } else if (id < 425984){                // BtW2 [256][512]
    int i2 = id - 294912; int n = i2 >> 9, k = i2 & 511;
    BtW2[i2] = f2bf(W2[(size_t)k * 256 + n]);
  } else if (id < 819200){                // BtG1 [768][512]
    int i2 = id - 425984; int j = i2 >> 9, k = i2 & 511;
    float v;
    if (k < 256){
      v = (j < 256) ? Wr[k * 256 + j] : (j < 512) ? Wz[k * 256 + (j - 256)] : Wh[k * 256 + (j - 512)];
    } else {
      int kk = k - 256;
      v = (j < 256) ? Ur[kk * 256 + j] : (j < 512) ? Uz[kk * 256 + (j - 256)] : 0.f;
    }
    BtG1[i2] = f2bf(v);
  } else if (id < 884736){                // BtUh [256][256]
    int i2 = id - 819200; int n = i2 >> 8, k = i2 & 255;
    BtUh[i2] = f2bf(Uh[(size_t)k * 256 + n]);
  }
}

// ------------------------------ GRU elementwise ----------------------------
__global__ __launch_bounds__(256)
void gru_elem1(const float* __restrict__ G1, const float* __restrict__ h,
               const float* __restrict__ br, const float* __restrict__ bz,
               short* __restrict__ rh, float* __restrict__ zbuf)
{
  int gi = blockIdx.x * 256 + threadIdx.x;
  int row = gi >> 6, c = (gi & 63) << 2;
  f32x4 gr  = *(const f32x4*)(G1 + (size_t)row * 768 + c);
  f32x4 gz  = *(const f32x4*)(G1 + (size_t)row * 768 + 256 + c);
  f32x4 hv  = *(const f32x4*)(h  + (size_t)row * 256 + c);
  f32x4 brv = *(const f32x4*)(br + c);
  f32x4 bzv = *(const f32x4*)(bz + c);
  s16x4 rhv; f32x4 zv;
#pragma unroll
  for (int jj = 0; jj < 4; ++jj){
    float r = 1.f / (1.f + __expf(-(gr[jj] + brv[jj])));
    float z = 1.f / (1.f + __expf(-(gz[jj] + bzv[jj])));
    rhv[jj] = f2bf(r * hv[jj]);
    zv[jj]  = z;
  }
  *(s16x4*)(rh  + (size_t)row * 256 + c) = rhv;
  *(f32x4*)(zbuf + (size_t)row * 256 + c) = zv;
}
__global__ __launch_bounds__(256)
void gru_elem2(const float* __restrict__ G1, const float* __restrict__ G2,
               const float* __restrict__ zbuf, const float* __restrict__ bh,
               float* __restrict__ h, short* __restrict__ mh)
{
  int gi = blockIdx.x * 256 + threadIdx.x;
  int row = gi >> 6, c = (gi & 63) << 2;
  f32x4 pw  = *(const f32x4*)(G1 + (size_t)row * 768 + 512 + c);
  f32x4 g2  = *(const f32x4*)(G2 + (size_t)row * 256 + c);
  f32x4 bhv = *(const f32x4*)(bh + c);
  f32x4 zv  = *(const f32x4*)(zbuf + (size_t)row * 256 + c);
  f32x4 hv  = *(const f32x4*)(h + (size_t)row * 256 + c);
  f32x4 hn; s16x4 hb;
#pragma unroll
  for (int jj = 0; jj < 4; ++jj){
    float ht = tanhf(pw[jj] + g2[jj] + bhv[jj]);
    float x  = (1.f - zv[jj]) * hv[jj] + zv[jj] * ht;
    hn[jj] = x; hb[jj] = f2bf(x);
  }
  *(f32x4*)(h + (size_t)row * 256 + c) = hn;
  *(s16x4*)(mh + (size_t)row * 512 + 256 + c) = hb;
}

// -------------------------------- readout ----------------------------------
__global__ __launch_bounds__(256)
void readout1(const float* __restrict__ h, float* __restrict__ g){
  int t = threadIdx.x;
  float a0 = 0.f, a1 = 0.f;
  int n0 = blockIdx.x * 32;
  for (int n = n0; n < n0 + 32; ++n){
    const float* hp = h + (size_t)n * 512;
    a0 += hp[t];
    a1 += hp[t + 256];
  }
  atomicAdd(&g[t], a0);
  atomicAdd(&g[t + 256], a1);
}
__global__ __launch_bounds__(256)
void readout2(const float* __restrict__ g, const float* __restrict__ Wo,
              const float* __restrict__ bo, float* __restrict__ out){
  int t = threadIdx.x;
  int b = t >> 7, o = t & 127;
  float s = bo[o];
  for (int c = 0; c < 256; ++c) s += g[b * 256 + c] * Wo[c * 128 + o];
  out[b * 128 + o] = s;
}

// ===========================================================================
extern "C" void kernel_launch(void* const* d_in, const int* in_sizes, int n_in,
                              void* d_out, int out_size, void* d_ws, size_t ws_size,
                              hipStream_t stream)
{
  const float* ef  = (const float*)d_in[0];
  const float* W1  = (const float*)d_in[1];
  const float* b1  = (const float*)d_in[2];
  const float* W2  = (const float*)d_in[3];
  const float* b2  = (const float*)d_in[4];
  const float* Wr  = (const float*)d_in[5];
  const float* Ur  = (const float*)d_in[6];
  const float* br  = (const float*)d_in[7];
  const float* Wz  = (const float*)d_in[8];
  const float* Uz  = (const float*)d_in[9];
  const float* bz  = (const float*)d_in[10];
  const float* Wh  = (const float*)d_in[11];
  const float* Uh  = (const float*)d_in[12];
  const float* bh  = (const float*)d_in[13];
  const float* Wo  = (const float*)d_in[14];
  const float* bo  = (const float*)d_in[15];
  const int* esrc  = (const int*)d_in[16];
  const int* edst  = (const int*)d_in[17];

  char* base = (char*)d_ws;
  size_t off = 0;
  auto alloc = [&](size_t bytes) -> char* {
    off = (off + 255) & ~(size_t)255;
    char* p = base + off;
    off += bytes;
    return p;
  };
  float* h    = (float*)alloc((size_t)NB * 256 * 4);
  float* m    = (float*)alloc((size_t)NB * 256 * 4);
  short* mh   = (short*)alloc((size_t)NB * 512 * 2);   // [m_bf | h_bf]
  short* P    = (short*)alloc((size_t)NB * 1024 * 2);  // [P1 | P2]
  short* S    = (short*)alloc((size_t)NB * 512 * 2);
  float* G1   = (float*)alloc((size_t)NB * 768 * 4);
  float* G2   = (float*)alloc((size_t)NB * 256 * 4);
  short* rh   = (short*)alloc((size_t)NB * 256 * 2);
  float* zb   = (float*)alloc((size_t)NB * 256 * 4);
  short* ebf  = (short*)alloc((size_t)E_EDGES * 2 * EDIM * 2);
  short* BtP  = (short*)alloc(262144 * 2);
  short* BtE  = (short*)alloc(32768 * 2);
  short* BtW2 = (short*)alloc(131072 * 2);
  short* BtG1 = (short*)alloc(393216 * 2);
  short* BtUh = (short*)alloc(65536 * 2);
  int* counts = (int*)alloc(NNODES * 4);
  int* rs     = (int*)alloc((NNODES + 1) * 4);
  int* cursor = (int*)alloc(NNODES * 4);
  int* ceid   = (int*)alloc(E_EDGES * 4);
  int* csrc   = (int*)alloc(E_EDGES * 4);
  float* g    = (float*)alloc(512 * 4);
  off = (off + 255) & ~(size_t)255;
  size_t avail = ws_size > off ? ws_size - off : 0;
  short* E1 = (short*)(base + off);

  // E1 chunking: full is 268 MB; fall back to per-iter chunked recompute.
  size_t e1_full = (size_t)E_EDGES * 2 * MLPH * 2;
  int nchunks = 1;
  size_t cap_edges = E_EDGES;
  if (avail < e1_full){
    nchunks = 0;
    for (int nc = 2; nc <= 64; nc <<= 1){
      size_t cap = (size_t)((double)E_EDGES / nc * 1.25) + 256;
      if (cap * 2 * MLPH * 2 <= avail){ nchunks = nc; cap_edges = cap; break; }
    }
    if (!nchunks){ nchunks = 64; cap_edges = avail / (2 * MLPH * 2); }
  }

  dim3 blk(256);

  // ------------------------------- prep ----------------------------------
  hipMemsetAsync(h,  0, (size_t)NB * 256 * 4, stream);
  hipMemsetAsync(m,  0, (size_t)NB * 256 * 4, stream);
  hipMemsetAsync(mh, 0, (size_t)NB * 512 * 2, stream);
  hipMemsetAsync(g,  0, 512 * 4, stream);
  hipMemsetAsync(counts, 0, NNODES * 4, stream);
  prep_weights<<<3456, blk, 0, stream>>>(W1, W2, Wr, Ur, Wz, Uz, Wh, Uh,
                                         BtP, BtE, BtW2, BtG1, BtUh);
  cvt_ef<<<(E_EDGES * 2 * EDIM) / (256 * 8), blk, 0, stream>>>(ef, ebf);
  count_kernel<<<512, blk, 0, stream>>>(edst, counts);
  scan_kernel<<<1, 1024, 0, stream>>>(counts, rs, cursor);
  fill_kernel<<<512, blk, 0, stream>>>(edst, esrc, cursor, ceid, csrc);

  auto launch_e1 = [&](int n0, int n1, size_t capE){
    int gx = (int)((2 * capE + 127) / 128);
    gemm128<0, true><<<dim3(gx, MLPH / 128), blk, 0, stream>>>(
        ebf, EDIM, BtE, EDIM, nullptr, E1, 0, MLPH, b1,
        nullptr, nullptr, ceid, rs, n0, n1);
  };
  if (nchunks == 1) launch_e1(0, NNODES, E_EDGES);   // iteration-invariant

  // ----------------------------- iterations ------------------------------
  for (int it = 0; it < NIT; ++it){
    // P = h @ [A1 | A2]   (A = h_bf = mh cols 256..511)
    gemm128<0, false><<<dim3(128, 8), blk, 0, stream>>>(
        mh + 256, 512, BtP, 256, nullptr, P, 0, 1024, nullptr,
        nullptr, nullptr, nullptr, nullptr, 0, 0);

    if (nchunks == 1){
      edge_kernel<<<NNODES, blk, 0, stream>>>(P, E1, csrc, rs, S, 0);
    } else {
      int npc = NNODES / nchunks;
      for (int c = 0; c < nchunks; ++c){
        launch_e1(c * npc, (c + 1) * npc, cap_edges);
        edge_kernel<<<npc, blk, 0, stream>>>(P, E1, csrc, rs, S, c * npc);
      }
    }

    // m += S @ W2 + deg*b2 ; write fp32 m and bf16 into mh[:,0:256]
    gemm128<1, false><<<dim3(128, 2), blk, 0, stream>>>(
        S, 512, BtW2, 512, m, mh, 256, 512, nullptr,
        counts, b2, nullptr, nullptr, 0, 0);

    // G1 = [m|h] @ [[Wr|Wz|Wh],[Ur|Uz|0]]
    gemm128<2, false><<<dim3(128, 6), blk, 0, stream>>>(
        mh, 512, BtG1, 512, G1, nullptr, 768, 0, nullptr,
        nullptr, nullptr, nullptr, nullptr, 0, 0);

    gru_elem1<<<4096, blk, 0, stream>>>(G1, h, br, bz, rh, zb);

    // G2 = (r*h) @ Uh
    gemm128<2, false><<<dim3(128, 2), blk, 0, stream>>>(
        rh, 256, BtUh, 256, G2, nullptr, 256, 0, nullptr,
        nullptr, nullptr, nullptr, nullptr, 0, 0);

    gru_elem2<<<4096, blk, 0, stream>>>(G1, G2, zb, bh, h, mh);
  }

  // ------------------------------ readout --------------------------------
  readout1<<<256, blk, 0, stream>>>(h, g);
  readout2<<<1, blk, 0, stream>>>(g, Wo, bo, (float*)d_out);
}

// Round 3
// 946.152 us; speedup vs baseline: 2.3256x; 2.0290x over previous
//
#include <hip/hip_runtime.h>
#include <hip/hip_bf16.h>

#define E_EDGES 131072
#define NNODES  8192
#define NB      16384   // N_NODES * BATCH rows
#define HID     256
#define EDIM    64
#define MLPH    512
#define OUTD    128
#define NIT     3
#define RB      32      // rows per node_update block

typedef short s16x4 __attribute__((ext_vector_type(4)));
typedef short s16x8 __attribute__((ext_vector_type(8)));
typedef float f32x4 __attribute__((ext_vector_type(4)));

__device__ __forceinline__ short f2bf(float f){
  unsigned int x = __builtin_bit_cast(unsigned int, f);
  x += 0x7fffu + ((x >> 16) & 1u);          // RNE
  return (short)(x >> 16);
}
__device__ __forceinline__ float bf2f(short s){
  unsigned int x = ((unsigned int)(unsigned short)s) << 16;
  return __builtin_bit_cast(float, x);
}
__device__ __forceinline__ void gload_lds16(const void* g, void* l){
  __builtin_amdgcn_global_load_lds(
      (const __attribute__((address_space(1))) void*)g,
      (__attribute__((address_space(3))) void*)l, 16, 0, 0);
}

// ===========================================================================
// Fused node update: for 32 rows, computes
//   A: m += S@W2^T + deg*b2          (Ms <- bf16(m))
//   B: Gr = [m|h]@BtRZ[0:256]        C: Gz = [m|h]@BtRZ[256:512]
//   e1: r,z; Xs <- bf16(r*h)
//   D: Gw = [m|rh]@BtHW
//   e2: h' = (1-z)h + z*tanh(Gw+bh); Ms <- bf16(h')
//   E: P = h'@BtP (4 panels of 256)         [LAST: readout partial instead]
// LDS tiles XOR-swizzled (16B-unit ^= row&7) to kill 16-way read conflicts;
// staging uses pre-swizzled GLOBAL source + linear global_load_lds dest.
// ===========================================================================
template<int LAST>
__global__ __launch_bounds__(256, 2)
void node_update(const short* __restrict__ S, float* __restrict__ m,
                 float* __restrict__ h, short* __restrict__ hbg,
                 short* __restrict__ P, float* __restrict__ g,
                 const short* __restrict__ BtW2, const short* __restrict__ BtRZ,
                 const short* __restrict__ BtHW, const short* __restrict__ BtP,
                 const int* __restrict__ deg, const float* __restrict__ b2,
                 const float* __restrict__ br, const float* __restrict__ bz,
                 const float* __restrict__ bh)
{
  __shared__ __align__(16) char lds[69632];
  short* As = (short*)lds;             // [32][64]   4KB  (S staging)
  short* Bs = (short*)(lds + 4096);    // [256][64] 32KB  (B-panel staging)
  short* Ms = (short*)(lds + 36864);   // [32][256] 16KB  (m_bf, later h'_bf)
  short* Xs = (short*)(lds + 53248);   // [32][256] 16KB  (hb, later rh_bf)
  float* Hf = (float*)lds;             // [32][256] 32KB  overlay (LAST only)

  const int tid = threadIdx.x;
  const int w = tid >> 6, l = tid & 63;
  const int lr = l & 15, lg = l >> 4;
  const int grow0 = blockIdx.x * RB;

  auto stageB = [&](const short* Bt, int K, int pcol0, int k0){
#pragma unroll
    for (int i = 0; i < 8; ++i){
      int u = i * 256 + tid;
      int row = u >> 3, uc = u & 7;
      const short* gp = Bt + (size_t)(pcol0 + row) * K + k0 + ((uc ^ (row & 7)) << 3);
      gload_lds16(gp, (char*)Bs + i * 4096 + w * 1024);
    }
  };
  auto stageA_S = [&](int k0){
    int row = tid >> 3, uc = tid & 7;
    const short* gp = S + (size_t)(grow0 + row) * 512 + k0 + ((uc ^ (row & 7)) << 3);
    gload_lds16(gp, (char*)As + w * 1024);
  };
  // element addr with 16B-unit XOR swizzle
  auto rdA64 = [&](int row, int colel){ return row * 64 + (colel ^ ((row & 7) << 3)); };
  auto rd256 = [&](int row, int colel){ return row * 256 + (colel ^ ((row & 7) << 3)); };

  // ---- preload hb tile into Xs (pre-swizzled source, linear dest) ----
#pragma unroll
  for (int i = 0; i < 4; ++i){
    int u = i * 256 + tid;
    int row = u >> 5, uc = u & 31;
    const short* gp = hbg + (size_t)(grow0 + row) * 256 + ((uc ^ (row & 7)) << 3);
    gload_lds16(gp, (char*)Xs + i * 4096 + w * 1024);
  }

  // ---------------- Phase A: m update ----------------
  f32x4 acc[2][4];
#pragma unroll
  for (int i = 0; i < 2; ++i)
#pragma unroll
    for (int j = 0; j < 4; ++j) acc[i][j] = (f32x4){0.f,0.f,0.f,0.f};

  for (int c = 0; c < 8; ++c){
    __syncthreads();
    stageA_S(c * 64);
    stageB(BtW2, 512, 0, c * 64);
    __syncthreads();
#pragma unroll
    for (int kk = 0; kk < 2; ++kk){
      s16x8 a[2], b[4];
#pragma unroll
      for (int i = 0; i < 2; ++i) a[i] = *(const s16x8*)(As + rdA64(i*16+lr, kk*32+lg*8));
#pragma unroll
      for (int j = 0; j < 4; ++j) b[j] = *(const s16x8*)(Bs + rdA64(w*64+j*16+lr, kk*32+lg*8));
#pragma unroll
      for (int i = 0; i < 2; ++i)
#pragma unroll
        for (int j = 0; j < 4; ++j)
          acc[i][j] = __builtin_amdgcn_mfma_f32_16x16x32_bf16(a[i], b[j], acc[i][j], 0,0,0);
    }
  }
  // epilogue A: fp32 m r/w + Ms bf16
#pragma unroll
  for (int i = 0; i < 2; ++i)
#pragma unroll
    for (int j = 0; j < 4; ++j)
#pragma unroll
      for (int r = 0; r < 4; ++r){
        int rl = i*16 + lg*4 + r, colp = w*64 + j*16 + lr;
        size_t gi = (size_t)(grow0 + rl) * 256 + colp;
        float v = acc[i][j][r] + m[gi] + (float)deg[(grow0 + rl) >> 1] * b2[colp];
        if (!LAST) m[gi] = v;
        Ms[rd256(rl, colp)] = f2bf(v);
      }

  // ---------------- Phase B: Gr ----------------
  f32x4 Gr[2][4], Gz[2][4];
#pragma unroll
  for (int i = 0; i < 2; ++i)
#pragma unroll
    for (int j = 0; j < 4; ++j){ Gr[i][j] = (f32x4){0.f,0.f,0.f,0.f}; Gz[i][j] = (f32x4){0.f,0.f,0.f,0.f}; }

  for (int c = 0; c < 8; ++c){
    __syncthreads();
    stageB(BtRZ, 512, 0, c * 64);
    __syncthreads();
    const short* Ab = (c < 4) ? Ms : Xs;
    int kb = (c & 3) * 64;
#pragma unroll
    for (int kk = 0; kk < 2; ++kk){
      s16x8 a[2], b[4];
#pragma unroll
      for (int i = 0; i < 2; ++i) a[i] = *(const s16x8*)(Ab + rd256(i*16+lr, kb + kk*32+lg*8));
#pragma unroll
      for (int j = 0; j < 4; ++j) b[j] = *(const s16x8*)(Bs + rdA64(w*64+j*16+lr, kk*32+lg*8));
#pragma unroll
      for (int i = 0; i < 2; ++i)
#pragma unroll
        for (int j = 0; j < 4; ++j)
          Gr[i][j] = __builtin_amdgcn_mfma_f32_16x16x32_bf16(a[i], b[j], Gr[i][j], 0,0,0);
    }
  }
  // ---------------- Phase C: Gz ----------------
  for (int c = 0; c < 8; ++c){
    __syncthreads();
    stageB(BtRZ, 512, 256, c * 64);
    __syncthreads();
    const short* Ab = (c < 4) ? Ms : Xs;
    int kb = (c & 3) * 64;
#pragma unroll
    for (int kk = 0; kk < 2; ++kk){
      s16x8 a[2], b[4];
#pragma unroll
      for (int i = 0; i < 2; ++i) a[i] = *(const s16x8*)(Ab + rd256(i*16+lr, kb + kk*32+lg*8));
#pragma unroll
      for (int j = 0; j < 4; ++j) b[j] = *(const s16x8*)(Bs + rdA64(w*64+j*16+lr, kk*32+lg*8));
#pragma unroll
      for (int i = 0; i < 2; ++i)
#pragma unroll
        for (int j = 0; j < 4; ++j)
          Gz[i][j] = __builtin_amdgcn_mfma_f32_16x16x32_bf16(a[i], b[j], Gz[i][j], 0,0,0);
    }
  }

  // ---------------- elementwise 1: r, z, rh ----------------
  __syncthreads();                     // all hb reads done before Xs overwrite
  f32x4 zz[2][4], hv[2][4];
#pragma unroll
  for (int i = 0; i < 2; ++i)
#pragma unroll
    for (int j = 0; j < 4; ++j)
#pragma unroll
      for (int r = 0; r < 4; ++r){
        int rl = i*16 + lg*4 + r, colp = w*64 + j*16 + lr;
        size_t gi = (size_t)(grow0 + rl) * 256 + colp;
        float hvv = h[gi];
        float rr = 1.f / (1.f + __expf(-(Gr[i][j][r] + br[colp])));
        float z  = 1.f / (1.f + __expf(-(Gz[i][j][r] + bz[colp])));
        hv[i][j][r] = hvv; zz[i][j][r] = z;
        Xs[rd256(rl, colp)] = f2bf(rr * hvv);
      }
  __syncthreads();

  // ---------------- Phase D: Gw ----------------
  f32x4 Gw[2][4];
#pragma unroll
  for (int i = 0; i < 2; ++i)
#pragma unroll
    for (int j = 0; j < 4; ++j) Gw[i][j] = (f32x4){0.f,0.f,0.f,0.f};
  for (int c = 0; c < 8; ++c){
    __syncthreads();
    stageB(BtHW, 512, 0, c * 64);
    __syncthreads();
    const short* Ab = (c < 4) ? Ms : Xs;
    int kb = (c & 3) * 64;
#pragma unroll
    for (int kk = 0; kk < 2; ++kk){
      s16x8 a[2], b[4];
#pragma unroll
      for (int i = 0; i < 2; ++i) a[i] = *(const s16x8*)(Ab + rd256(i*16+lr, kb + kk*32+lg*8));
#pragma unroll
      for (int j = 0; j < 4; ++j) b[j] = *(const s16x8*)(Bs + rdA64(w*64+j*16+lr, kk*32+lg*8));
#pragma unroll
      for (int i = 0; i < 2; ++i)
#pragma unroll
        for (int j = 0; j < 4; ++j)
          Gw[i][j] = __builtin_amdgcn_mfma_f32_16x16x32_bf16(a[i], b[j], Gw[i][j], 0,0,0);
    }
  }

  // ---------------- elementwise 2: h' ----------------
  __syncthreads();                     // D's Ms reads done before overwrite
#pragma unroll
  for (int i = 0; i < 2; ++i)
#pragma unroll
    for (int j = 0; j < 4; ++j)
#pragma unroll
      for (int r = 0; r < 4; ++r){
        int rl = i*16 + lg*4 + r, colp = w*64 + j*16 + lr;
        size_t gi = (size_t)(grow0 + rl) * 256 + colp;
        float ht = tanhf(Gw[i][j][r] + bh[colp]);
        float z = zz[i][j][r];
        float hn = (1.f - z) * hv[i][j][r] + z * ht;
        if (!LAST){
          h[gi] = hn;
          hbg[gi] = f2bf(hn);
          Ms[rd256(rl, colp)] = f2bf(hn);
        } else {
          Hf[rl * 256 + colp] = hn;
        }
      }
  __syncthreads();

  if (!LAST){
    // ---------------- Phase E: P = h' @ BtP (4 panels) ----------------
    for (int pn = 0; pn < 4; ++pn){
      f32x4 pe[2][4];
#pragma unroll
      for (int i = 0; i < 2; ++i)
#pragma unroll
        for (int j = 0; j < 4; ++j) pe[i][j] = (f32x4){0.f,0.f,0.f,0.f};
      for (int c = 0; c < 4; ++c){
        __syncthreads();
        stageB(BtP, 256, pn * 256, c * 64);
        __syncthreads();
#pragma unroll
        for (int kk = 0; kk < 2; ++kk){
          s16x8 a[2], b[4];
#pragma unroll
          for (int i = 0; i < 2; ++i) a[i] = *(const s16x8*)(Ms + rd256(i*16+lr, c*64 + kk*32+lg*8));
#pragma unroll
          for (int j = 0; j < 4; ++j) b[j] = *(const s16x8*)(Bs + rdA64(w*64+j*16+lr, kk*32+lg*8));
#pragma unroll
          for (int i = 0; i < 2; ++i)
#pragma unroll
            for (int j = 0; j < 4; ++j)
              pe[i][j] = __builtin_amdgcn_mfma_f32_16x16x32_bf16(a[i], b[j], pe[i][j], 0,0,0);
        }
      }
#pragma unroll
      for (int i = 0; i < 2; ++i)
#pragma unroll
        for (int j = 0; j < 4; ++j)
#pragma unroll
          for (int r = 0; r < 4; ++r){
            int rl = i*16 + lg*4 + r, colp = w*64 + j*16 + lr;
            P[(size_t)(grow0 + rl) * 1024 + pn * 256 + colp] = f2bf(pe[i][j][r]);
          }
    }
  } else {
    // ---------------- readout partial: g[b*256+c] += sum rows ----------------
    float s0 = 0.f, s1 = 0.f;
#pragma unroll
    for (int rl = 0; rl < 32; rl += 2){
      s0 += Hf[rl * 256 + tid];
      s1 += Hf[(rl + 1) * 256 + tid];
    }
    atomicAdd(&g[tid], s0);
    atomicAdd(&g[256 + tid], s1);
  }
}

// ---------------------------------------------------------------------------
// E1 gather GEMM (round-2 structure, write-bound): E1[p] = ebf[eid[p]]@BtE + b1
// ---------------------------------------------------------------------------
template<int MODE, bool GATHER>
__global__ __launch_bounds__(256, 3)
void gemm128(const short* __restrict__ A, int lda, const short* __restrict__ Bt,
             int K, short* __restrict__ Cbf, int ldcbf,
             const float* __restrict__ bias,
             const int* __restrict__ gat, const int* __restrict__ row_start,
             int node0, int node1)
{
  __shared__ __align__(16) short As[128 * 64];
  __shared__ __align__(16) short Bs[128 * 64];

  int p0 = 0, mrows = 1 << 30;
  if (GATHER){
    p0 = row_start[node0];
    mrows = 2 * (row_start[node1] - p0);
    if ((int)blockIdx.x * 128 >= mrows) return;
  }
  const int t  = threadIdx.x;
  const int w  = t >> 6, l = t & 63;
  const int lr = l & 15, lg = l >> 4;
  const int wr = w >> 1, wc = w & 1;
  const int browbase = blockIdx.x * 128;
  const int bcolbase = blockIdx.y * 128;
  const int srow = t >> 3;
  const int scol = (t & 7) * 8;

  f32x4 acc[4][4];
#pragma unroll
  for (int mm = 0; mm < 4; ++mm)
#pragma unroll
    for (int n = 0; n < 4; ++n) acc[mm][n] = (f32x4){0.f,0.f,0.f,0.f};

  for (int k0 = 0; k0 < K; k0 += 64){
    __syncthreads();
#pragma unroll
    for (int i = 0; i < 4; ++i){
      int row = srow + i * 32;
      const short* gp;
      if (GATHER){
        int R = browbase + row;
        int p = p0 + (R >> 1);
        if (p > E_EDGES - 1) p = E_EDGES - 1;
        int e = gat[p];
        gp = A + (size_t)(e * 2 + (R & 1)) * lda + scol;
      } else {
        gp = A + (size_t)(browbase + row) * lda + k0 + scol;
      }
      gload_lds16(gp, (char*)As + w * 1024 + i * 4096);
    }
#pragma unroll
    for (int i = 0; i < 4; ++i){
      const short* gp = Bt + (size_t)(bcolbase + srow + i * 32) * K + k0 + scol;
      gload_lds16(gp, (char*)Bs + w * 1024 + i * 4096);
    }
    __syncthreads();

#pragma unroll
    for (int kk = 0; kk < 2; ++kk){
      s16x8 a[4], b[4];
#pragma unroll
      for (int mm = 0; mm < 4; ++mm)
        a[mm] = *(const s16x8*)(As + (wr*64 + mm*16 + lr) * 64 + kk*32 + lg*8);
#pragma unroll
      for (int n = 0; n < 4; ++n)
        b[n] = *(const s16x8*)(Bs + (wc*64 + n*16 + lr) * 64 + kk*32 + lg*8);
#pragma unroll
      for (int mm = 0; mm < 4; ++mm)
#pragma unroll
        for (int n = 0; n < 4; ++n)
          acc[mm][n] = __builtin_amdgcn_mfma_f32_16x16x32_bf16(a[mm], b[n], acc[mm][n], 0,0,0);
    }
  }
#pragma unroll
  for (int mm = 0; mm < 4; ++mm){
    int orow0 = browbase + wr*64 + mm*16 + lg*4;
#pragma unroll
    for (int n = 0; n < 4; ++n){
      int ocol = bcolbase + wc*64 + n*16 + lr;
#pragma unroll
      for (int r = 0; r < 4; ++r){
        int orow = orow0 + r;
        if (!GATHER || orow < mrows){
          float v = acc[mm][n][r] + (bias ? bias[ocol] : 0.f);
          Cbf[(size_t)orow * ldcbf + ocol] = f2bf(v);
        }
      }
    }
  }
}

// --------------------------- ef -> bf16 conversion -------------------------
__global__ __launch_bounds__(256)
void cvt_ef(const float* __restrict__ ef, short* __restrict__ ebf){
  size_t i = (size_t)(blockIdx.x * 256 + threadIdx.x) * 8;
  f32x4 f0 = *(const f32x4*)(ef + i);
  f32x4 f1 = *(const f32x4*)(ef + i + 4);
  s16x8 o;
  o[0]=f2bf(f0[0]); o[1]=f2bf(f0[1]); o[2]=f2bf(f0[2]); o[3]=f2bf(f0[3]);
  o[4]=f2bf(f1[0]); o[5]=f2bf(f1[1]); o[6]=f2bf(f1[2]); o[7]=f2bf(f1[3]);
  *(s16x8*)(ebf + i) = o;
}

// ---------------------------------------------------------------------------
// Per-node CSR edge kernel: S[n] = sum_{e: dst=n} relu(P1[n] + P2[src] + E1[e])
// ---------------------------------------------------------------------------
template<bool USE_P>
__global__ __launch_bounds__(256)
void edge_kernel(const short* __restrict__ P, const short* __restrict__ E1,
                 const int* __restrict__ csr_src, const int* __restrict__ row_start,
                 short* __restrict__ S, int node0)
{
  const int n = node0 + blockIdx.x;
  const int t = threadIdx.x;
  const int b = t >> 7;
  const int j = (t & 127) << 2;
  const int p0 = row_start[node0];
  const int ps = row_start[n], pe = row_start[n + 1];

  float p10 = 0.f, p11 = 0.f, p12 = 0.f, p13 = 0.f;
  if (USE_P){
    s16x4 t1 = *(const s16x4*)(P + (size_t)(n * 2 + b) * 1024 + j);
    p10 = bf2f(t1[0]); p11 = bf2f(t1[1]); p12 = bf2f(t1[2]); p13 = bf2f(t1[3]);
  }
  float a0 = 0.f, a1 = 0.f, a2 = 0.f, a3 = 0.f;
  for (int p = ps; p < pe; ++p){
    s16x4 v1 = *(const s16x4*)(E1 + (size_t)((p - p0) * 2 + b) * 512 + j);
    float x0 = p10 + bf2f(v1[0]);
    float x1 = p11 + bf2f(v1[1]);
    float x2 = p12 + bf2f(v1[2]);
    float x3 = p13 + bf2f(v1[3]);
    if (USE_P){
      int src = csr_src[p];
      s16x4 v2 = *(const s16x4*)(P + (size_t)(src * 2 + b) * 1024 + 512 + j);
      x0 += bf2f(v2[0]); x1 += bf2f(v2[1]); x2 += bf2f(v2[2]); x3 += bf2f(v2[3]);
    }
    a0 += fmaxf(x0, 0.f); a1 += fmaxf(x1, 0.f);
    a2 += fmaxf(x2, 0.f); a3 += fmaxf(x3, 0.f);
  }
  s16x4 o; o[0] = f2bf(a0); o[1] = f2bf(a1); o[2] = f2bf(a2); o[3] = f2bf(a3);
  *(s16x4*)(S + (size_t)(n * 2 + b) * 512 + j) = o;
}

// ------------------------------- CSR build ---------------------------------
__global__ void count_kernel(const int* __restrict__ edst, int* __restrict__ counts){
  int e = blockIdx.x * 256 + threadIdx.x;
  if (e < E_EDGES) atomicAdd(&counts[edst[e]], 1);
}
__global__ void scan_kernel(const int* __restrict__ counts, int* __restrict__ row_start,
                            int* __restrict__ cursor){
  __shared__ int sums[1024];
  int t = threadIdx.x;
  int base = t * 8;
  int loc[8]; int s = 0;
#pragma unroll
  for (int i = 0; i < 8; ++i){ loc[i] = s; s += counts[base + i]; }
  sums[t] = s;
  __syncthreads();
  for (int o = 1; o < 1024; o <<= 1){
    int v = sums[t];
    int u = (t >= o) ? sums[t - o] : 0;
    __syncthreads();
    sums[t] = v + u;
    __syncthreads();
  }
  int excl = (t == 0) ? 0 : sums[t - 1];
#pragma unroll
  for (int i = 0; i < 8; ++i){ int v = excl + loc[i]; row_start[base + i] = v; cursor[base + i] = v; }
  if (t == 1023) row_start[NNODES] = sums[1023];
}
__global__ void fill_kernel(const int* __restrict__ edst, const int* __restrict__ esrc,
                            int* __restrict__ cursor, int* __restrict__ csr_eid,
                            int* __restrict__ csr_src){
  int e = blockIdx.x * 256 + threadIdx.x;
  if (e < E_EDGES){
    int pos = atomicAdd(&cursor[edst[e]], 1);
    csr_eid[pos] = e;
    csr_src[pos] = esrc[e];
  }
}

// --------------------------- weight repacking ------------------------------
// BtP [1024][256], BtE [512][64], BtW2 [256][512],
// BtRZ [512][512] (cols r|z, K = W|U), BtHW [256][512] (K = Wh|Uh)
__global__ void prep_weights(const float* __restrict__ W1, const float* __restrict__ W2,
                             const float* __restrict__ Wr, const float* __restrict__ Ur,
                             const float* __restrict__ Wz, const float* __restrict__ Uz,
                             const float* __restrict__ Wh, const float* __restrict__ Uh,
                             short* __restrict__ BtP, short* __restrict__ BtE,
                             short* __restrict__ BtW2, short* __restrict__ BtRZ,
                             short* __restrict__ BtHW)
{
  int id = blockIdx.x * 256 + threadIdx.x;
  if (id < 262144){                       // BtP
    int jj = id >> 8, k = id & 255;
    float v = (jj < 512) ? W1[(size_t)k * 512 + jj] : W1[(size_t)(256 + k) * 512 + (jj - 512)];
    BtP[id] = f2bf(v);
  } else if (id < 294912){                // BtE
    int i2 = id - 262144; int jj = i2 >> 6, c = i2 & 63;
    BtE[i2] = f2bf(W1[(size_t)(512 + c) * 512 + jj]);
  } else if (id < 425984){                // BtW2
    int i2 = id - 294912; int n = i2 >> 9, k = i2 & 511;
    BtW2[i2] = f2bf(W2[(size_t)k * 256 + n]);
  } else if (id < 688128){                // BtRZ
    int i2 = id - 425984; int col = i2 >> 9, k = i2 & 511;
    float v;
    if (col < 256) v = (k < 256) ? Wr[(size_t)k * 256 + col] : Ur[(size_t)(k - 256) * 256 + col];
    else { int c2 = col - 256; v = (k < 256) ? Wz[(size_t)k * 256 + c2] : Uz[(size_t)(k - 256) * 256 + c2]; }
    BtRZ[i2] = f2bf(v);
  } else if (id < 819200){                // BtHW
    int i2 = id - 688128; int col = i2 >> 9, k = i2 & 511;
    float v = (k < 256) ? Wh[(size_t)k * 256 + col] : Uh[(size_t)(k - 256) * 256 + col];
    BtHW[i2] = f2bf(v);
  }
}

// -------------------------------- readout ----------------------------------
__global__ __launch_bounds__(256)
void readout2(const float* __restrict__ g, const float* __restrict__ Wo,
              const float* __restrict__ bo, float* __restrict__ out){
  int t = threadIdx.x;
  int b = t >> 7, o = t & 127;
  float s = bo[o];
  for (int c = 0; c < 256; ++c) s += g[b * 256 + c] * Wo[c * 128 + o];
  out[b * 128 + o] = s;
}

// ===========================================================================
extern "C" void kernel_launch(void* const* d_in, const int* in_sizes, int n_in,
                              void* d_out, int out_size, void* d_ws, size_t ws_size,
                              hipStream_t stream)
{
  const float* ef  = (const float*)d_in[0];
  const float* W1  = (const float*)d_in[1];
  const float* b1  = (const float*)d_in[2];
  const float* W2  = (const float*)d_in[3];
  const float* b2  = (const float*)d_in[4];
  const float* Wr  = (const float*)d_in[5];
  const float* Ur  = (const float*)d_in[6];
  const float* br  = (const float*)d_in[7];
  const float* Wz  = (const float*)d_in[8];
  const float* Uz  = (const float*)d_in[9];
  const float* bz  = (const float*)d_in[10];
  const float* Wh  = (const float*)d_in[11];
  const float* Uh  = (const float*)d_in[12];
  const float* bh  = (const float*)d_in[13];
  const float* Wo  = (const float*)d_in[14];
  const float* bo  = (const float*)d_in[15];
  const int* esrc  = (const int*)d_in[16];
  const int* edst  = (const int*)d_in[17];

  char* base = (char*)d_ws;
  size_t off = 0;
  auto alloc = [&](size_t bytes) -> char* {
    off = (off + 255) & ~(size_t)255;
    char* p = base + off;
    off += bytes;
    return p;
  };
  float* h    = (float*)alloc((size_t)NB * 256 * 4);
  float* m    = (float*)alloc((size_t)NB * 256 * 4);
  short* hb   = (short*)alloc((size_t)NB * 256 * 2);
  short* S    = (short*)alloc((size_t)NB * 512 * 2);
  short* P    = (short*)alloc((size_t)NB * 1024 * 2);
  short* ebf  = (short*)alloc((size_t)E_EDGES * 2 * EDIM * 2);
  short* BtP  = (short*)alloc(262144 * 2);
  short* BtE  = (short*)alloc(32768 * 2);
  short* BtW2 = (short*)alloc(131072 * 2);
  short* BtRZ = (short*)alloc(262144 * 2);
  short* BtHW = (short*)alloc(131072 * 2);
  int* counts = (int*)alloc(NNODES * 4);
  int* rs     = (int*)alloc((NNODES + 1) * 4);
  int* cursor = (int*)alloc(NNODES * 4);
  int* ceid   = (int*)alloc(E_EDGES * 4);
  int* csrc   = (int*)alloc(E_EDGES * 4);
  float* g    = (float*)alloc(512 * 4);
  off = (off + 255) & ~(size_t)255;
  size_t avail = ws_size > off ? ws_size - off : 0;
  short* E1 = (short*)(base + off);

  size_t e1_full = (size_t)E_EDGES * 2 * MLPH * 2;
  int nchunks = 1;
  size_t cap_edges = E_EDGES;
  if (avail < e1_full){
    nchunks = 0;
    for (int nc = 2; nc <= 64; nc <<= 1){
      size_t cap = (size_t)((double)E_EDGES / nc * 1.25) + 256;
      if (cap * 2 * MLPH * 2 <= avail){ nchunks = nc; cap_edges = cap; break; }
    }
    if (!nchunks){ nchunks = 64; cap_edges = avail / (2 * MLPH * 2); }
  }

  dim3 blk(256);

  // ------------------------------- prep ----------------------------------
  hipMemsetAsync(h,  0, (size_t)NB * 256 * 4, stream);
  hipMemsetAsync(m,  0, (size_t)NB * 256 * 4, stream);
  hipMemsetAsync(hb, 0, (size_t)NB * 256 * 2, stream);
  hipMemsetAsync(g,  0, 512 * 4, stream);
  hipMemsetAsync(counts, 0, NNODES * 4, stream);
  prep_weights<<<3200, blk, 0, stream>>>(W1, W2, Wr, Ur, Wz, Uz, Wh, Uh,
                                         BtP, BtE, BtW2, BtRZ, BtHW);
  cvt_ef<<<(E_EDGES * 2 * EDIM) / (256 * 8), blk, 0, stream>>>(ef, ebf);
  count_kernel<<<512, blk, 0, stream>>>(edst, counts);
  scan_kernel<<<1, 1024, 0, stream>>>(counts, rs, cursor);
  fill_kernel<<<512, blk, 0, stream>>>(edst, esrc, cursor, ceid, csrc);

  auto launch_e1 = [&](int n0, int n1, size_t capE){
    int gx = (int)((2 * capE + 127) / 128);
    gemm128<0, true><<<dim3(gx, MLPH / 128), blk, 0, stream>>>(
        ebf, EDIM, BtE, EDIM, E1, MLPH, b1, ceid, rs, n0, n1);
  };
  if (nchunks == 1) launch_e1(0, NNODES, E_EDGES);

  // ----------------------------- iterations ------------------------------
  for (int it = 0; it < NIT; ++it){
    if (nchunks == 1){
      if (it == 0) edge_kernel<false><<<NNODES, blk, 0, stream>>>(P, E1, csrc, rs, S, 0);
      else         edge_kernel<true ><<<NNODES, blk, 0, stream>>>(P, E1, csrc, rs, S, 0);
    } else {
      int npc = NNODES / nchunks;
      for (int c = 0; c < nchunks; ++c){
        launch_e1(c * npc, (c + 1) * npc, cap_edges);
        if (it == 0) edge_kernel<false><<<npc, blk, 0, stream>>>(P, E1, csrc, rs, S, c * npc);
        else         edge_kernel<true ><<<npc, blk, 0, stream>>>(P, E1, csrc, rs, S, c * npc);
      }
    }
    if (it == NIT - 1)
      node_update<1><<<NB / RB, blk, 0, stream>>>(S, m, h, hb, P, g,
          BtW2, BtRZ, BtHW, BtP, counts, b2, br, bz, bh);
    else
      node_update<0><<<NB / RB, blk, 0, stream>>>(S, m, h, hb, P, g,
          BtW2, BtRZ, BtHW, BtP, counts, b2, br, bz, bh);
  }

  // ------------------------------ readout --------------------------------
  readout2<<<1, blk, 0, stream>>>(g, Wo, bo, (float*)d_out);
}